// Round 1
// baseline (26.890 us; speedup 1.0000x reference)
//
#include <hip/hip_runtime.h>

// Time2Vec: out[b,s, i*64+j] = (j==0) ? (x[b,s,i]*w[i,j]+b[i,j])
//                                     : sin(x[b,s,i]*w[i,j]+b[i,j])
// B=32, S=2048, D=8, E=64  ->  ROWS=65536 rows of 512 f32 outputs.

constexpr int D_IN  = 8;
constexpr int E_PER = 64;
constexpr int CHANS = D_IN * E_PER;      // 512
constexpr int ROWS  = 32 * 2048;         // 65536
constexpr int TOTAL = ROWS * CHANS;      // 33,554,432 (fits int32)

__global__ __launch_bounds__(256) void time2vec_kernel(
    const float* __restrict__ x,      // [ROWS, 8]
    const float* __restrict__ w,      // [8, 64]
    const float* __restrict__ b,      // [8, 64]
    float* __restrict__ out)          // [ROWS, 512]
{
    const int tid      = blockIdx.x * blockDim.x + threadIdx.x;
    const int nthreads = gridDim.x * blockDim.x;     // multiple of 128 -> stride % 512 == 0

    // Channel within the 512-wide row is loop-invariant for this thread.
    const int c = (tid * 4) & (CHANS - 1);
    const int i = c >> 6;        // which input feature (0..7)
    const int j = c & 63;        // column within the 64-wide embed (multiple of 4)

    const float4 w4 = *reinterpret_cast<const float4*>(w + i * E_PER + j);
    const float4 b4 = *reinterpret_cast<const float4*>(b + i * E_PER + j);
    const bool lin0 = (j == 0);  // only element 0 of the float4 can be the linear column

    const int stride = nthreads * 4;
    for (int o = tid * 4; o < TOTAL; o += stride) {
        const int row = o >> 9;                    // o / 512
        const float xv = x[row * D_IN + i];

        const float a0 = fmaf(xv, w4.x, b4.x);
        const float a1 = fmaf(xv, w4.y, b4.y);
        const float a2 = fmaf(xv, w4.z, b4.z);
        const float a3 = fmaf(xv, w4.w, b4.w);

        float4 r;
        r.x = lin0 ? a0 : __sinf(a0);
        r.y = __sinf(a1);
        r.z = __sinf(a2);
        r.w = __sinf(a3);

        *reinterpret_cast<float4*>(out + o) = r;
    }
}

extern "C" void kernel_launch(void* const* d_in, const int* in_sizes, int n_in,
                              void* d_out, int out_size, void* d_ws, size_t ws_size,
                              hipStream_t stream) {
    const float* x = (const float*)d_in[0];
    const float* w = (const float*)d_in[1];
    const float* b = (const float*)d_in[2];
    float* out = (float*)d_out;

    // 2048 blocks x 256 threads = 524,288 threads; 8.39M float4s -> 16 iters/thread.
    dim3 grid(2048), block(256);
    time2vec_kernel<<<grid, block, 0, stream>>>(x, w, b, out);
}